// Round 1
// baseline (401.676 us; speedup 1.0000x reference)
//
#include <hip/hip_runtime.h>
#include <math.h>

#define NPTS 200000
#define KNBR 16
#define CDIM 32
#define TEMP 0.1f
#define WEIGHT 0.1f
#define EPSV 1e-8f

__global__ __launch_bounds__(256) void contrast_main(
    const float* __restrict__ features,
    const int* __restrict__ labels,
    const int* __restrict__ nbr,
    float* __restrict__ ws)   // ws[0] = loss sum, ws[1] = valid count
{
    const int t = threadIdx.x;
    const int grp = t >> 4;          // point within block (0..15)
    const int k = t & 15;            // neighbor lane (0..15)
    const int p = blockIdx.x * 16 + grp;

    float loss = 0.f;
    float validf = 0.f;

    if (p < NPTS) {
        // coalesced: nbr[p*16+k] == nbr[blockIdx*256 + t]
        const int idx = nbr[p * KNBR + k];
        const int lab_c = labels[p];
        const int lab_n = labels[idx];
        const bool pos = (lab_n == lab_c);

        const float4* __restrict__ fc = (const float4*)(features + (size_t)p * CDIM);
        const float4* __restrict__ fn = (const float4*)(features + (size_t)idx * CDIM);

        float acc = 0.f;
        #pragma unroll
        for (int j = 0; j < CDIM / 4; ++j) {
            float4 a = fc[j];
            float4 b = fn[j];
            float dx = a.x - b.x;
            float dy = a.y - b.y;
            float dz = a.z - b.z;
            float dw = a.w - b.w;
            acc += dx * dx + dy * dy + dz * dz + dw * dw;
        }
        const float dist = sqrtf(acc + EPSV);

        // min distance across the 16 lanes of this point (== max of d = -dist)
        float mind = dist;
        #pragma unroll
        for (int off = 8; off >= 1; off >>= 1)
            mind = fminf(mind, __shfl_xor(mind, off, 16));

        const float e = expf((mind - dist) / TEMP);
        float negs = e;
        float poss = pos ? e : 0.f;
        float cnts = pos ? 1.f : 0.f;
        #pragma unroll
        for (int off = 8; off >= 1; off >>= 1) {
            negs += __shfl_xor(negs, off, 16);
            poss += __shfl_xor(poss, off, 16);
            cnts += __shfl_xor(cnts, off, 16);
        }

        if (k == 0) {
            const int icnt = (int)(cnts + 0.5f);
            if (icnt > 0 && icnt < KNBR) {
                loss = -logf(poss / negs + EPSV);
                validf = 1.f;
            }
        }
    }

    __shared__ float s_loss;
    __shared__ float s_cnt;
    if (t == 0) { s_loss = 0.f; s_cnt = 0.f; }
    __syncthreads();
    if (validf != 0.f) {
        atomicAdd(&s_loss, loss);
        atomicAdd(&s_cnt, validf);
    }
    __syncthreads();
    if (t == 0) {
        atomicAdd(&ws[0], s_loss);
        atomicAdd(&ws[1], s_cnt);
    }
}

__global__ void contrast_finalize(const float* __restrict__ ws,
                                  float* __restrict__ out)
{
    const float denom = fmaxf(ws[1], 1.f);
    out[0] = ws[0] / denom * WEIGHT;
}

extern "C" void kernel_launch(void* const* d_in, const int* in_sizes, int n_in,
                              void* d_out, int out_size, void* d_ws, size_t ws_size,
                              hipStream_t stream) {
    const float* features = (const float*)d_in[0];
    const int* labels     = (const int*)d_in[1];
    const int* nbr        = (const int*)d_in[2];
    float* out = (float*)d_out;
    float* ws  = (float*)d_ws;

    // zero the two accumulators (ws is re-poisoned to 0xAA before every call)
    hipMemsetAsync(ws, 0, 2 * sizeof(float), stream);

    const int blocks = (NPTS + 15) / 16;   // 12500
    contrast_main<<<blocks, 256, 0, stream>>>(features, labels, nbr, ws);
    contrast_finalize<<<1, 1, 0, stream>>>(ws, out);
}